// Round 4
// baseline (5087.625 us; speedup 1.0000x reference)
//
#include <hip/hip_runtime.h>
#include <cstdint>
#include <cstddef>

// ============================================================================
// disciminativeAno R4: b128 LDS reads (float4-granular XOR swizzle),
// wave-uniform co-groups (s_load weights), occupancy-tuned blocks.
// FMA order per output kept identical to R3 (absmax was 0.0).
// ============================================================================

// ---------------------------------------------------------------------------
// conv1: x[C,32,32,3] -> h1[C,16,16,32]  (unchanged from R3)
// ---------------------------------------------------------------------------
__global__ __launch_bounds__(256) void k_conv1(const float* __restrict__ x,
    const float* __restrict__ w, const float* __restrict__ bb,
    const float* __restrict__ sc, const float* __restrict__ of,
    float* __restrict__ out) {
  const int b = blockIdx.x;
  const int pos = threadIdx.x;
  const int oy = pos >> 4, ox = pos & 15;
  float acc[32];
#pragma unroll
  for (int c = 0; c < 32; ++c) acc[c] = 0.f;
  const float* xb = x + (size_t)b * 3072;
#pragma unroll 1
  for (int ky = 0; ky < 5; ++ky) {
    const int iy = 2 * oy - 1 + ky;
    if ((unsigned)iy >= 32u) continue;
#pragma unroll 1
    for (int kx = 0; kx < 5; ++kx) {
      const int ix = 2 * ox - 1 + kx;
      if ((unsigned)ix >= 32u) continue;
      const float* xp = xb + (iy * 32 + ix) * 3;
#pragma unroll
      for (int ci = 0; ci < 3; ++ci) {
        const float v = xp[ci];
        const float* wp = w + ((ky * 5 + kx) * 3 + ci) * 32;
#pragma unroll
        for (int c = 0; c < 32; ++c) acc[c] = fmaf(v, wp[c], acc[c]);
      }
    }
  }
  float* op = out + ((size_t)b * 256 + pos) * 32;
#pragma unroll
  for (int c = 0; c < 32; ++c) {
    const float v = fmaxf(acc[c] + bb[c], 0.f);
    op[c] = v * sc[c] + of[c];
  }
}

// ---------------------------------------------------------------------------
// conv2: h1[C,16,16,32] -> h2[C,8,8,64]. 1 img, 32 KB, f4-swizzle.
// lanes = 64 out-pos; waves = 4 co-groups of 16. acc[16]. b128 reads.
// ---------------------------------------------------------------------------
__global__ __launch_bounds__(256) void k_conv2(const float* __restrict__ in,
    const float* __restrict__ w, const float* __restrict__ bb,
    const float* __restrict__ sc, const float* __restrict__ of,
    float* __restrict__ out) {
  __shared__ float4 tile4[2048];         // 256 pix * 8 f4 = 32 KB
  const int b = blockIdx.x;
  const int tid = threadIdx.x;
#pragma unroll
  for (int q = 0; q < 8; ++q) {
    const int f4 = tid + q * 256;
    const int pix = f4 >> 3, g4 = f4 & 7;
    const int s4 = (((pix >> 4) * 5) + (pix & 15)) & 7;
    tile4[pix * 8 + (g4 ^ s4)] = ((const float4*)(in + (size_t)b * 8192))[f4];
  }
  __syncthreads();
  const int pos = tid & 63;
  const int chg = __builtin_amdgcn_readfirstlane(tid >> 6);
  const int co0 = chg * 16;
  const int oy = pos >> 3, ox = pos & 7;
  float acc[16];
#pragma unroll
  for (int c = 0; c < 16; ++c) acc[c] = 0.f;
#pragma unroll 1
  for (int ky = 0; ky < 5; ++ky) {
    const int iy = 2 * oy - 1 + ky;
#pragma unroll 1
    for (int kx = 0; kx < 5; ++kx) {
      const int ix = 2 * ox - 1 + kx;
      const bool valid = ((unsigned)iy < 16u) && ((unsigned)ix < 16u);
      const int pix = valid ? (iy * 16 + ix) : 0;
      const int s4 = (((pix >> 4) * 5) + (pix & 15)) & 7;
      const float* wt = w + ((size_t)(ky * 5 + kx) * 32) * 64 + co0;
#pragma unroll
      for (int g4 = 0; g4 < 8; ++g4) {
        float4 a = tile4[pix * 8 + (g4 ^ s4)];
        a.x = valid ? a.x : 0.f; a.y = valid ? a.y : 0.f;
        a.z = valid ? a.z : 0.f; a.w = valid ? a.w : 0.f;
        const float av[4] = {a.x, a.y, a.z, a.w};
#pragma unroll
        for (int j = 0; j < 4; ++j) {
          const float* wp = wt + (g4 * 4 + j) * 64;
#pragma unroll
          for (int c = 0; c < 16; ++c) acc[c] = fmaf(av[j], wp[c], acc[c]);
        }
      }
    }
  }
  float* op = out + ((size_t)b * 64 + pos) * 64 + co0;
#pragma unroll
  for (int c = 0; c < 16; ++c) {
    const float v = fmaxf(acc[c] + bb[co0 + c], 0.f);
    op[c] = v * sc[co0 + c] + of[co0 + c];
  }
}

// ---------------------------------------------------------------------------
// conv3: h2[C,8,8,64] -> h3[C,4,4,128]. 512 thr, 4 img, 64 KB full-ci.
// lanes = (img,pos); waves = 8 co-groups of 16. acc[16]. b128 reads.
// ---------------------------------------------------------------------------
__global__ __launch_bounds__(512) void k_conv3(const float* __restrict__ in,
    const float* __restrict__ w, const float* __restrict__ bb,
    const float* __restrict__ sc, const float* __restrict__ of,
    float* __restrict__ out) {
  __shared__ float4 tile4[4096];         // 4 img * 64 pix * 16 f4 = 64 KB
  const int b0 = blockIdx.x * 4;
  const int tid = threadIdx.x;
#pragma unroll
  for (int q = 0; q < 8; ++q) {
    const int f4 = tid + q * 512;
    const int img = f4 >> 10, rem = f4 & 1023;
    const int pix = rem >> 4, g4 = rem & 15;
    const int s4 = (((pix >> 3) * 5) + (pix & 7) + img * 3) & 15;
    tile4[img * 1024 + pix * 16 + (g4 ^ s4)] =
        ((const float4*)(in + (size_t)(b0 + img) * 4096))[rem];
  }
  __syncthreads();
  const int lane = tid & 63;
  const int img = lane >> 4, pos = lane & 15;
  const int chg = __builtin_amdgcn_readfirstlane(tid >> 6);
  const int co0 = chg * 16;
  const int oy = pos >> 2, ox = pos & 3;
  float acc[16];
#pragma unroll
  for (int c = 0; c < 16; ++c) acc[c] = 0.f;
  const float4* tb = &tile4[img * 1024];
#pragma unroll 1
  for (int ky = 0; ky < 5; ++ky) {
    const int iy = 2 * oy - 1 + ky;
#pragma unroll 1
    for (int kx = 0; kx < 5; ++kx) {
      const int ix = 2 * ox - 1 + kx;
      const bool valid = ((unsigned)iy < 8u) && ((unsigned)ix < 8u);
      const int pix = valid ? (iy * 8 + ix) : 0;
      const int s4 = (((pix >> 3) * 5) + (pix & 7) + img * 3) & 15;
      const float* wt = w + ((size_t)(ky * 5 + kx) * 64) * 128 + co0;
#pragma unroll
      for (int g4 = 0; g4 < 16; ++g4) {
        float4 a = tb[pix * 16 + (g4 ^ s4)];
        a.x = valid ? a.x : 0.f; a.y = valid ? a.y : 0.f;
        a.z = valid ? a.z : 0.f; a.w = valid ? a.w : 0.f;
        const float av[4] = {a.x, a.y, a.z, a.w};
#pragma unroll
        for (int j = 0; j < 4; ++j) {
          const float* wp = wt + (g4 * 4 + j) * 128;
#pragma unroll
          for (int c = 0; c < 16; ++c) acc[c] = fmaf(av[j], wp[c], acc[c]);
        }
      }
    }
  }
  float* op = out + ((size_t)(b0 + img) * 16 + pos) * 128 + co0;
#pragma unroll
  for (int c = 0; c < 16; ++c) {
    const float v = fmaxf(acc[c] + bb[co0 + c], 0.f);
    op[c] = v * sc[co0 + c] + of[co0 + c];
  }
}

// ---------------------------------------------------------------------------
// fc_z (unchanged from R3)
// ---------------------------------------------------------------------------
__global__ __launch_bounds__(256) void k_fcz(const float* __restrict__ h3,
    const float* __restrict__ wzm, const float* __restrict__ bzm,
    const float* __restrict__ wzl, const float* __restrict__ bzl,
    const float* __restrict__ eps, float* __restrict__ z) {
  __shared__ float a[4 * 256];
  const int ib = blockIdx.x * 4;
  const int tid = threadIdx.x;
  const int co = tid & 127;
  const int grp = __builtin_amdgcn_readfirstlane(tid >> 7);
  float am[2], al[2];
#pragma unroll
  for (int i = 0; i < 2; ++i) { am[i] = 0.f; al[i] = 0.f; }
  for (int kc = 0; kc < 2048; kc += 256) {
    __syncthreads();
    {
      const int r = tid >> 6, c4 = (tid & 63) << 2;
      *(float4*)&a[r * 256 + c4] =
          *(const float4*)&h3[(size_t)(ib + r) * 2048 + kc + c4];
    }
    __syncthreads();
#pragma unroll 4
    for (int k = 0; k < 256; k += 4) {
      float wm[4], wl[4];
#pragma unroll
      for (int q = 0; q < 4; ++q) {
        wm[q] = wzm[(size_t)(kc + k + q) * 128 + co];
        wl[q] = wzl[(size_t)(kc + k + q) * 128 + co];
      }
#pragma unroll
      for (int i = 0; i < 2; ++i) {
        const float4 av = *(const float4*)&a[(grp * 2 + i) * 256 + k];
        am[i] = fmaf(av.x, wm[0], am[i]); am[i] = fmaf(av.y, wm[1], am[i]);
        am[i] = fmaf(av.z, wm[2], am[i]); am[i] = fmaf(av.w, wm[3], am[i]);
        al[i] = fmaf(av.x, wl[0], al[i]); al[i] = fmaf(av.y, wl[1], al[i]);
        al[i] = fmaf(av.z, wl[2], al[i]); al[i] = fmaf(av.w, wl[3], al[i]);
      }
    }
  }
#pragma unroll
  for (int i = 0; i < 2; ++i) {
    const int row = ib + grp * 2 + i;
    const float zm = fmaxf(am[i] + bzm[co], 0.f);
    const float zl = fmaxf(al[i] + bzl[co], 0.f);
    z[(size_t)row * 128 + co] = zm + expf(0.5f * zl) * eps[(size_t)row * 128 + co];
  }
}

// ---------------------------------------------------------------------------
// fc_dec: z[C,128] @ dw[128,8192] -> d[C,8192]. b128 z-reads.
// ---------------------------------------------------------------------------
__global__ __launch_bounds__(256) void k_fcdec(const float* __restrict__ z,
    const float* __restrict__ dw, const float* __restrict__ db,
    float* __restrict__ out) {
  __shared__ float4 zt4[2048];           // 64 img * 32 f4 = 32 KB
  const int bid = blockIdx.x;
  const int m0 = (bid >> 6) * 64;
  const int n0 = (bid & 63) * 128;
  const int tid = threadIdx.x;
#pragma unroll
  for (int q = 0; q < 8; ++q) {
    const int f4 = tid + q * 256;
    const int img = f4 >> 5, g4 = f4 & 31;
    const int s4 = (img * 5) & 31;
    zt4[img * 32 + (g4 ^ s4)] = ((const float4*)(z + (size_t)(m0) * 128))[f4];
  }
  __syncthreads();
  const int img = tid & 63;
  const int grp = __builtin_amdgcn_readfirstlane(tid >> 6);
  const int nb = n0 + grp * 32;
  const int s4 = (img * 5) & 31;
  float acc[32];
#pragma unroll
  for (int c = 0; c < 32; ++c) acc[c] = 0.f;
#pragma unroll
  for (int g4 = 0; g4 < 32; ++g4) {
    const float4 a = zt4[img * 32 + (g4 ^ s4)];
    const float av[4] = {a.x, a.y, a.z, a.w};
#pragma unroll
    for (int j = 0; j < 4; ++j) {
      const float* wp = dw + (size_t)(g4 * 4 + j) * 8192 + nb;
#pragma unroll
      for (int c = 0; c < 32; ++c) acc[c] = fmaf(av[j], wp[c], acc[c]);
    }
  }
  float* op = out + (size_t)(m0 + img) * 8192 + nb;
#pragma unroll
  for (int c = 0; c < 32; ++c) op[c] = fmaxf(acc[c] + db[nb + c], 0.f);
}

// ---------------------------------------------------------------------------
// convT1 1x1: d[C,8,8,128] -> t1[C,8,8,128]. b128 reads, acc[32].
// ---------------------------------------------------------------------------
__global__ __launch_bounds__(256) void k_tconv1(const float* __restrict__ in,
    const float* __restrict__ w, const float* __restrict__ bb,
    const float* __restrict__ sc, const float* __restrict__ of,
    float* __restrict__ out) {
  __shared__ float4 tile4[2048];         // 64 pix * 32 f4 = 32 KB
  const int b = blockIdx.x;
  const int tid = threadIdx.x;
#pragma unroll
  for (int q = 0; q < 8; ++q) {
    const int f4 = tid + q * 256;
    const int pix = f4 >> 5, g4 = f4 & 31;
    const int s4 = (pix * 5) & 31;
    tile4[pix * 32 + (g4 ^ s4)] = ((const float4*)(in + (size_t)b * 8192))[f4];
  }
  __syncthreads();
  const int pos = tid & 63;
  const int chg = __builtin_amdgcn_readfirstlane(tid >> 6);
  const int co0 = chg * 32;
  const int s4 = (pos * 5) & 31;
  float acc[32];
#pragma unroll
  for (int c = 0; c < 32; ++c) acc[c] = 0.f;
#pragma unroll
  for (int g4 = 0; g4 < 32; ++g4) {
    const float4 a = tile4[pos * 32 + (g4 ^ s4)];
    const float av[4] = {a.x, a.y, a.z, a.w};
#pragma unroll
    for (int j = 0; j < 4; ++j) {
      const float* wp = w + (g4 * 4 + j) * 128 + co0;
#pragma unroll
      for (int c = 0; c < 32; ++c) acc[c] = fmaf(av[j], wp[c], acc[c]);
    }
  }
  float* op = out + ((size_t)b * 64 + pos) * 128 + co0;
#pragma unroll
  for (int c = 0; c < 32; ++c) {
    const float v = fmaxf(acc[c] + bb[co0 + c], 0.f);
    op[c] = v * sc[co0 + c] + of[co0 + c];
  }
}

// ---------------------------------------------------------------------------
// convT2: t1[C,8,8,128] -> t2[C,16,16,64], unflipped s2. b128 reads.
// lanes = 64 input pos; waves = 4 co-groups of 16. acc[4][16].
// ---------------------------------------------------------------------------
__global__ __launch_bounds__(256) void k_tconv2(const float* __restrict__ in,
    const float* __restrict__ w, const float* __restrict__ bb,
    const float* __restrict__ sc, const float* __restrict__ of,
    float* __restrict__ out) {
  __shared__ float4 tile4[2048];         // 64 pix * 32 f4 = 32 KB
  const int b = blockIdx.x;
  const int tid = threadIdx.x;
#pragma unroll
  for (int q = 0; q < 8; ++q) {
    const int f4 = tid + q * 256;
    const int pix = f4 >> 5, g4 = f4 & 31;
    const int s4 = (pix * 5) & 31;
    tile4[pix * 32 + (g4 ^ s4)] = ((const float4*)(in + (size_t)b * 8192))[f4];
  }
  __syncthreads();
  const int pos = tid & 63;
  const int chg = __builtin_amdgcn_readfirstlane(tid >> 6);
  const int co0 = chg * 16;
  const int jy = pos >> 3, jx = pos & 7;
  float acc[4][16];
#pragma unroll
  for (int p = 0; p < 4; ++p)
#pragma unroll
    for (int c = 0; c < 16; ++c) acc[p][c] = 0.f;
  const int DY[9]  = {1,1,0,0,1,0,0,0,0};
  const int DX[9]  = {1,0,1,0,0,0,1,0,0};
  const int KYt[9] = {0,0,2,2,0,2,1,1,1};
  const int KXt[9] = {0,2,0,2,1,1,0,2,1};
  const int PHt[9] = {0,0,0,0,1,1,2,2,3};
#pragma unroll 1
  for (int t = 0; t < 9; ++t) {
    const int sy = jy - DY[t], sx = jx - DX[t];
    const bool valid = (sy >= 0) && (sx >= 0);
    const int pix = valid ? (sy * 8 + sx) : 0;
    const int s4 = (pix * 5) & 31;
    const int ph = PHt[t];
    const float* wt = w + ((size_t)(KYt[t] * 3 + KXt[t]) * 128) * 64 + co0;
#pragma unroll
    for (int g4 = 0; g4 < 32; ++g4) {
      float4 a = tile4[pix * 32 + (g4 ^ s4)];
      a.x = valid ? a.x : 0.f; a.y = valid ? a.y : 0.f;
      a.z = valid ? a.z : 0.f; a.w = valid ? a.w : 0.f;
      const float av[4] = {a.x, a.y, a.z, a.w};
#pragma unroll
      for (int j = 0; j < 4; ++j) {
        const float* wp = wt + (g4 * 4 + j) * 64;
#pragma unroll
        for (int c = 0; c < 16; ++c) acc[ph][c] = fmaf(av[j], wp[c], acc[ph][c]);
      }
    }
  }
#pragma unroll
  for (int py = 0; py < 2; ++py)
#pragma unroll
    for (int px = 0; px < 2; ++px) {
      const int oy = 2 * jy + py, ox = 2 * jx + px;
      float* op = out + (((size_t)b * 16 + oy) * 16 + ox) * 64 + co0;
#pragma unroll
      for (int c = 0; c < 16; ++c) {
        const float v = fmaxf(acc[py * 2 + px][c] + bb[co0 + c], 0.f);
        op[c] = v * sc[co0 + c] + of[co0 + c];
      }
    }
}

// ---------------------------------------------------------------------------
// convT3: t2[C,16,16,64] -> t3 (ci8-GROUPED layout [b][grp4][1024][8]).
// 512 thr, 8-row slab (+halo staged, dummy zero pixel), 4 blk/CU -> 32 w/CU.
// lanes = 128 input pos across 2 waves; wave-pair co-group of 8. acc[4][8].
// ---------------------------------------------------------------------------
__global__ __launch_bounds__(512) void k_tconv3(const float* __restrict__ in,
    const float* __restrict__ w, const float* __restrict__ bb,
    const float* __restrict__ sc, const float* __restrict__ of,
    float* __restrict__ t3g) {
  __shared__ float4 tile4[145 * 16];     // 9 rows *16 cols *16 f4 + dummy pix
  const int b = blockIdx.x >> 1;
  const int r0 = (blockIdx.x & 1) * 8;
  const int tid = threadIdx.x;
  for (int f4 = tid; f4 < 2304; f4 += 512) {
    const int rr = f4 >> 8;              // 0..8
    const int col = (f4 >> 4) & 15, g4 = f4 & 15;
    const int gy = r0 - 1 + rr;
    float4 v = make_float4(0.f, 0.f, 0.f, 0.f);
    if (gy >= 0)
      v = *(const float4*)&in[(((size_t)b * 16 + gy) * 16 + col) * 64 + g4 * 4];
    const int s4 = (rr * 5 + col) & 15;
    tile4[(rr * 16 + col) * 16 + (g4 ^ s4)] = v;
  }
  if (tid < 16) tile4[144 * 16 + tid] = make_float4(0.f, 0.f, 0.f, 0.f);
  __syncthreads();
  const int pos = tid & 127;
  const int prow = pos >> 4, pcol = pos & 15;
  const int chg = __builtin_amdgcn_readfirstlane(tid >> 7);
  const int co0 = chg * 8;
  float acc[4][8];
#pragma unroll
  for (int p = 0; p < 4; ++p)
#pragma unroll
    for (int c = 0; c < 8; ++c) acc[p][c] = 0.f;
  const int DY[9]  = {1,1,0,0,1,0,0,0,0};
  const int DX[9]  = {1,0,1,0,0,0,1,0,0};
  const int KYt[9] = {0,0,2,2,0,2,1,1,1};
  const int KXt[9] = {0,2,0,2,1,1,0,2,1};
  const int PHt[9] = {0,0,0,0,1,1,2,2,3};
#pragma unroll 1
  for (int t = 0; t < 9; ++t) {
    const int syst = prow + 1 - DY[t];   // 0..8, staged (halo handled)
    const int sx = pcol - DX[t];
    const bool vx = (sx >= 0);
    const int pix = vx ? (syst * 16 + sx) : 144;
    const int s4 = vx ? ((syst * 5 + sx) & 15) : 0;
    const int ph = PHt[t];
    const float* wt = w + ((size_t)(KYt[t] * 3 + KXt[t]) * 64) * 32 + co0;
#pragma unroll
    for (int g4 = 0; g4 < 16; ++g4) {
      const float4 a = tile4[pix * 16 + (g4 ^ s4)];
      const float av[4] = {a.x, a.y, a.z, a.w};
#pragma unroll
      for (int j = 0; j < 4; ++j) {
        const float* wp = wt + (g4 * 4 + j) * 32;
#pragma unroll
        for (int c = 0; c < 8; ++c) acc[ph][c] = fmaf(av[j], wp[c], acc[ph][c]);
      }
    }
  }
  const int jy = r0 + prow;
#pragma unroll
  for (int py = 0; py < 2; ++py)
#pragma unroll
    for (int px = 0; px < 2; ++px) {
      const int oy = 2 * jy + py, ox = 2 * pcol + px;
      float* op = t3g + ((size_t)b * 4 + chg) * 8192 + (size_t)(oy * 32 + ox) * 8;
      float vv[8];
#pragma unroll
      for (int c = 0; c < 8; ++c) {
        const float v = fmaxf(acc[py * 2 + px][c] + bb[co0 + c], 0.f);
        vv[c] = v * sc[co0 + c] + of[co0 + c];
      }
      *(float4*)&op[0] = make_float4(vv[0], vv[1], vv[2], vv[3]);
      *(float4*)&op[4] = make_float4(vv[4], vv[5], vv[6], vv[7]);
    }
}

// ---------------------------------------------------------------------------
// convT4 + sigmoid + error. Full image, 2x2 out-pixels/thread, 4 ci8 passes
// staged contiguously from grouped t3. Window as float4 regs.
// FMA order per output: ci ascending, then tap ascending (matches R3).
// ---------------------------------------------------------------------------
__global__ __launch_bounds__(256) void k_tconv4err(const float* __restrict__ t3g,
    const float* __restrict__ w, const float* __restrict__ bb,
    const float* __restrict__ x, float* __restrict__ err) {
  __shared__ float4 win4[34 * 65];       // [row -1..32][col][2 f4] + pad
  const int b = blockIdx.x;
  const int tid = threadIdx.x;
  const int ty = tid >> 4, tx = tid & 15;
  float acc[2][2][3];
#pragma unroll
  for (int dy = 0; dy < 2; ++dy)
#pragma unroll
    for (int dx = 0; dx < 2; ++dx)
#pragma unroll
      for (int c = 0; c < 3; ++c) acc[dy][dx][c] = 0.f;
#pragma unroll 1
  for (int g = 0; g < 4; ++g) {
    __syncthreads();
    for (int f4 = tid; f4 < 2176; f4 += 256) {
      const int rr = f4 >> 6;            // 0..33
      const int rem = f4 & 63;
      const int col = rem >> 1, h = rem & 1;
      const int gy = rr - 1;
      float4 v = make_float4(0.f, 0.f, 0.f, 0.f);
      if ((unsigned)gy < 32u)
        v = ((const float4*)(t3g + ((size_t)b * 4 + g) * 8192))[(gy * 32 + col) * 2 + h];
      win4[rr * 65 + col * 2 + h] = v;
    }
    __syncthreads();
#pragma unroll 1
    for (int h = 0; h < 2; ++h) {
      float4 W[4][4];
#pragma unroll
      for (int wy = 0; wy < 4; ++wy)
#pragma unroll
        for (int wx = 0; wx < 4; ++wx) {
          const int col = 2 * tx - 1 + wx;
          const bool edge = (wx == 0) || (wx == 3);
          const bool v = edge ? ((unsigned)col < 32u) : true;
          const int cc = v ? col : 0;
          float4 t = win4[(2 * ty + wy) * 65 + cc * 2 + h];
          if (edge) {
            t.x = v ? t.x : 0.f; t.y = v ? t.y : 0.f;
            t.z = v ? t.z : 0.f; t.w = v ? t.w : 0.f;
          }
          W[wy][wx] = t;
        }
#pragma unroll
      for (int j = 0; j < 4; ++j) {
        const int ci = g * 8 + h * 4 + j;
#pragma unroll
        for (int ky = 0; ky < 3; ++ky)
#pragma unroll
          for (int kx = 0; kx < 3; ++kx) {
            const float* wp = w + ((ky * 3 + kx) * 32 + ci) * 3;
            const float w0 = wp[0], w1 = wp[1], w2 = wp[2];
#pragma unroll
            for (int dy = 0; dy < 2; ++dy)
#pragma unroll
              for (int dx = 0; dx < 2; ++dx) {
                const float4 t = W[dy + ky][dx + kx];
                const float av = (j == 0) ? t.x : (j == 1) ? t.y : (j == 2) ? t.z : t.w;
                acc[dy][dx][0] = fmaf(av, w0, acc[dy][dx][0]);
                acc[dy][dx][1] = fmaf(av, w1, acc[dy][dx][1]);
                acc[dy][dx][2] = fmaf(av, w2, acc[dy][dx][2]);
              }
          }
      }
    }
  }
#pragma unroll
  for (int dy = 0; dy < 2; ++dy)
#pragma unroll
    for (int dx = 0; dx < 2; ++dx) {
      const int oy = 2 * ty + dy, ox = 2 * tx + dx;
      const size_t pidx = (size_t)b * 1024 + oy * 32 + ox;
      float e = 0.f;
#pragma unroll
      for (int c = 0; c < 3; ++c) {
        const float pre = acc[dy][dx][c] + bb[c];
        float r;
        if (pre >= 0.f) {
          r = 1.f / (1.f + expf(-pre));
        } else {
          const float ex = expf(pre);
          r = ex / (1.f + ex);
        }
        const float dd = x[pidx * 3 + c] - r;
        e += dd * dd;
      }
      err[pidx] = e / 3.0f;
    }
}

// ---------------------------------------------------------------------------
// Otsu (unchanged)
// ---------------------------------------------------------------------------
__global__ __launch_bounds__(256) void k_otsu(const float* __restrict__ err,
                                              int* __restrict__ outmask) {
  __shared__ float e[2][1024];
  __shared__ float sig[2][81];
  __shared__ float opti[2];
  const int b0 = blockIdx.x * 2;
  const int tid = threadIdx.x;
  for (int f4 = tid; f4 < 512; f4 += 256) {
    const int img = f4 >> 8, idx = (f4 & 255) << 2;
    *(float4*)&e[img][idx] = *(const float4*)&err[(size_t)(b0 + img) * 1024 + idx];
  }
  __syncthreads();
  const int img = tid >> 7, j = tid & 127;
  if (j < 81) {
    const float t = (float)(0.1 + (double)j * 0.01);
    float n0 = 0.f, n1 = 0.f, s0 = 0.f, s1 = 0.f;
    for (int i = 0; i < 1024; ++i) {
      const float v = e[img][i];
      if (v < t) {
        if (v != 0.f) { n0 += 1.f; s0 += v; }
      } else {
        n1 += 1.f; s1 += v;
      }
    }
    const float nt = n0 + n1;
    float m0 = (s0 / 1024.f) * (nt / n0);
    if (m0 != m0) m0 = 0.f;
    float m1 = (s1 / 1024.f) * (nt / n1);
    if (m1 != m1) m1 = 0.f;
    const float p0 = n0 / nt, p1 = n1 / nt;
    const float dm = m0 - m1;
    sig[img][j] = p0 * p1 * (dm * dm);
  }
  __syncthreads();
  if (j == 0) {
    float smax = 0.f, op = 0.f;
    for (int jj = 0; jj < 81; ++jj) {
      const float sb = sig[img][jj];
      const float t = (float)(0.1 + (double)jj * 0.01);
      if (sb >= smax) { smax = sb; op = t; }
    }
    opti[img] = op;
  }
  __syncthreads();
#pragma unroll
  for (int q = 0; q < 8; ++q) {
    const int idx = tid + q * 256;
    const int im = idx >> 10, p = idx & 1023;
    outmask[(size_t)(b0 + im) * 1024 + p] = (e[im][p] < opti[im]) ? 1 : 0;
  }
}

// ============================================================================
extern "C" void kernel_launch(void* const* d_in, const int* in_sizes, int n_in,
                              void* d_out, int out_size, void* d_ws, size_t ws_size,
                              hipStream_t stream) {
  (void)in_sizes; (void)n_in; (void)out_size;
  const float* x    = (const float*)d_in[0];
  const float* eps  = (const float*)d_in[1];
  const float* ew1  = (const float*)d_in[2];
  const float* eb1  = (const float*)d_in[3];
  const float* es1  = (const float*)d_in[4];
  const float* eo1  = (const float*)d_in[5];
  const float* ew2  = (const float*)d_in[6];
  const float* eb2  = (const float*)d_in[7];
  const float* es2  = (const float*)d_in[8];
  const float* eo2  = (const float*)d_in[9];
  const float* ew3  = (const float*)d_in[10];
  const float* eb3  = (const float*)d_in[11];
  const float* es3  = (const float*)d_in[12];
  const float* eo3  = (const float*)d_in[13];
  const float* wzm  = (const float*)d_in[14];
  const float* bzm  = (const float*)d_in[15];
  const float* wzl  = (const float*)d_in[16];
  const float* bzl  = (const float*)d_in[17];
  const float* dw   = (const float*)d_in[18];
  const float* db   = (const float*)d_in[19];
  const float* tw1  = (const float*)d_in[20];
  const float* tb1  = (const float*)d_in[21];
  const float* ds1  = (const float*)d_in[22];
  const float* do1  = (const float*)d_in[23];
  const float* tw2  = (const float*)d_in[24];
  const float* tb2  = (const float*)d_in[25];
  const float* ds2  = (const float*)d_in[26];
  const float* do2  = (const float*)d_in[27];
  const float* tw3  = (const float*)d_in[28];
  const float* tb3  = (const float*)d_in[29];
  const float* ds3  = (const float*)d_in[30];
  const float* do3  = (const float*)d_in[31];
  const float* tw4  = (const float*)d_in[32];
  const float* tb4  = (const float*)d_in[33];
  int* mask = (int*)d_out;

  const size_t per_img_bytes = 233472;
  int C = 64;
  const int cand[6] = {4096, 2048, 1024, 512, 256, 128};
  for (int i = 0; i < 6; ++i) {
    if ((size_t)cand[i] * per_img_bytes <= ws_size) { C = cand[i]; break; }
  }

  float* p0 = (float*)d_ws;                       // C*32768 floats (h1|d|t3g)
  float* p1 = p0 + (size_t)C * 32768;             // C*8192  (h2|z|t1)
  float* p2 = p1 + (size_t)C * 8192;              // C*16384 (h3|t2)
  float* p3 = p2 + (size_t)C * 16384;             // C*1024  (err)

  for (int c0 = 0; c0 < 4096; c0 += C) {
    const float* xc   = x   + (size_t)c0 * 3072;
    const float* epsc = eps + (size_t)c0 * 128;
    int*         mc   = mask + (size_t)c0 * 1024;
    float* h1 = p0;  float* dd = p0;  float* t3 = p0;
    float* h2 = p1;  float* zz = p1;  float* t1 = p1;
    float* h3 = p2;  float* t2 = p2;
    float* er = p3;

    k_conv1    <<<C,      256, 0, stream>>>(xc, ew1, eb1, es1, eo1, h1);
    k_conv2    <<<C,      256, 0, stream>>>(h1, ew2, eb2, es2, eo2, h2);
    k_conv3    <<<C / 4,  512, 0, stream>>>(h2, ew3, eb3, es3, eo3, h3);
    k_fcz      <<<C / 4,  256, 0, stream>>>(h3, wzm, bzm, wzl, bzl, epsc, zz);
    k_fcdec    <<<C,      256, 0, stream>>>(zz, dw, db, dd);
    k_tconv1   <<<C,      256, 0, stream>>>(dd, tw1, tb1, ds1, do1, t1);
    k_tconv2   <<<C,      256, 0, stream>>>(t1, tw2, tb2, ds2, do2, t2);
    k_tconv3   <<<C * 2,  512, 0, stream>>>(t2, tw3, tb3, ds3, do3, t3);
    k_tconv4err<<<C,      256, 0, stream>>>(t3, tw4, tb4, xc, er);
    k_otsu     <<<C / 2,  256, 0, stream>>>(er, mc);
  }
}

// Round 5
// 3809.069 us; speedup vs baseline: 1.3357x; 1.3357x over previous
//
#include <hip/hip_runtime.h>
#include <cstdint>
#include <cstddef>

// ============================================================================
// disciminativeAno R5: R4 + (a) tconv2 -> channel-grouped t2 with full-line
// coalesced stores (kills 3.4x write amplification / L2 RMW), (b) tap loops
// fully unrolled again (compile-time tables), g4 loop unroll 2.
// FMA order per output unchanged (absmax 0.0 preserved).
// ============================================================================

// ---------------------------------------------------------------------------
// conv1: x[C,32,32,3] -> h1[C,16,16,32]
// ---------------------------------------------------------------------------
__global__ __launch_bounds__(256) void k_conv1(const float* __restrict__ x,
    const float* __restrict__ w, const float* __restrict__ bb,
    const float* __restrict__ sc, const float* __restrict__ of,
    float* __restrict__ out) {
  const int b = blockIdx.x;
  const int pos = threadIdx.x;
  const int oy = pos >> 4, ox = pos & 15;
  float acc[32];
#pragma unroll
  for (int c = 0; c < 32; ++c) acc[c] = 0.f;
  const float* xb = x + (size_t)b * 3072;
#pragma unroll 1
  for (int ky = 0; ky < 5; ++ky) {
    const int iy = 2 * oy - 1 + ky;
    if ((unsigned)iy >= 32u) continue;
#pragma unroll 1
    for (int kx = 0; kx < 5; ++kx) {
      const int ix = 2 * ox - 1 + kx;
      if ((unsigned)ix >= 32u) continue;
      const float* xp = xb + (iy * 32 + ix) * 3;
#pragma unroll
      for (int ci = 0; ci < 3; ++ci) {
        const float v = xp[ci];
        const float* wp = w + ((ky * 5 + kx) * 3 + ci) * 32;
#pragma unroll
        for (int c = 0; c < 32; ++c) acc[c] = fmaf(v, wp[c], acc[c]);
      }
    }
  }
  float* op = out + ((size_t)b * 256 + pos) * 32;
#pragma unroll
  for (int c = 0; c < 32; ++c) {
    const float v = fmaxf(acc[c] + bb[c], 0.f);
    op[c] = v * sc[c] + of[c];
  }
}

// ---------------------------------------------------------------------------
// conv2: h1[C,16,16,32] -> h2[C,8,8,64]. b128 reads.
// ---------------------------------------------------------------------------
__global__ __launch_bounds__(256) void k_conv2(const float* __restrict__ in,
    const float* __restrict__ w, const float* __restrict__ bb,
    const float* __restrict__ sc, const float* __restrict__ of,
    float* __restrict__ out) {
  __shared__ float4 tile4[2048];         // 256 pix * 8 f4 = 32 KB
  const int b = blockIdx.x;
  const int tid = threadIdx.x;
#pragma unroll
  for (int q = 0; q < 8; ++q) {
    const int f4 = tid + q * 256;
    const int pix = f4 >> 3, g4 = f4 & 7;
    const int s4 = (((pix >> 4) * 5) + (pix & 15)) & 7;
    tile4[pix * 8 + (g4 ^ s4)] = ((const float4*)(in + (size_t)b * 8192))[f4];
  }
  __syncthreads();
  const int pos = tid & 63;
  const int chg = __builtin_amdgcn_readfirstlane(tid >> 6);
  const int co0 = chg * 16;
  const int oy = pos >> 3, ox = pos & 7;
  float acc[16];
#pragma unroll
  for (int c = 0; c < 16; ++c) acc[c] = 0.f;
#pragma unroll 1
  for (int ky = 0; ky < 5; ++ky) {
    const int iy = 2 * oy - 1 + ky;
#pragma unroll 1
    for (int kx = 0; kx < 5; ++kx) {
      const int ix = 2 * ox - 1 + kx;
      const bool valid = ((unsigned)iy < 16u) && ((unsigned)ix < 16u);
      const int pix = valid ? (iy * 16 + ix) : 0;
      const int s4 = (((pix >> 4) * 5) + (pix & 15)) & 7;
      const float* wt = w + ((size_t)(ky * 5 + kx) * 32) * 64 + co0;
#pragma unroll
      for (int g4 = 0; g4 < 8; ++g4) {
        float4 a = tile4[pix * 8 + (g4 ^ s4)];
        a.x = valid ? a.x : 0.f; a.y = valid ? a.y : 0.f;
        a.z = valid ? a.z : 0.f; a.w = valid ? a.w : 0.f;
        const float av[4] = {a.x, a.y, a.z, a.w};
#pragma unroll
        for (int j = 0; j < 4; ++j) {
          const float* wp = wt + (g4 * 4 + j) * 64;
#pragma unroll
          for (int c = 0; c < 16; ++c) acc[c] = fmaf(av[j], wp[c], acc[c]);
        }
      }
    }
  }
  float* op = out + ((size_t)b * 64 + pos) * 64 + co0;
#pragma unroll
  for (int c = 0; c < 16; ++c) {
    const float v = fmaxf(acc[c] + bb[co0 + c], 0.f);
    op[c] = v * sc[co0 + c] + of[co0 + c];
  }
}

// ---------------------------------------------------------------------------
// conv3: h2[C,8,8,64] -> h3[C,4,4,128]. 512 thr, 4 img, 64 KB. b128 reads.
// ---------------------------------------------------------------------------
__global__ __launch_bounds__(512) void k_conv3(const float* __restrict__ in,
    const float* __restrict__ w, const float* __restrict__ bb,
    const float* __restrict__ sc, const float* __restrict__ of,
    float* __restrict__ out) {
  __shared__ float4 tile4[4096];         // 64 KB
  const int b0 = blockIdx.x * 4;
  const int tid = threadIdx.x;
#pragma unroll
  for (int q = 0; q < 8; ++q) {
    const int f4 = tid + q * 512;
    const int img = f4 >> 10, rem = f4 & 1023;
    const int pix = rem >> 4, g4 = rem & 15;
    const int s4 = (((pix >> 3) * 5) + (pix & 7) + img * 3) & 15;
    tile4[img * 1024 + pix * 16 + (g4 ^ s4)] =
        ((const float4*)(in + (size_t)(b0 + img) * 4096))[rem];
  }
  __syncthreads();
  const int lane = tid & 63;
  const int img = lane >> 4, pos = lane & 15;
  const int chg = __builtin_amdgcn_readfirstlane(tid >> 6);
  const int co0 = chg * 16;
  const int oy = pos >> 2, ox = pos & 3;
  float acc[16];
#pragma unroll
  for (int c = 0; c < 16; ++c) acc[c] = 0.f;
  const float4* tb = &tile4[img * 1024];
#pragma unroll 1
  for (int ky = 0; ky < 5; ++ky) {
    const int iy = 2 * oy - 1 + ky;
#pragma unroll 1
    for (int kx = 0; kx < 5; ++kx) {
      const int ix = 2 * ox - 1 + kx;
      const bool valid = ((unsigned)iy < 8u) && ((unsigned)ix < 8u);
      const int pix = valid ? (iy * 8 + ix) : 0;
      const int s4 = (((pix >> 3) * 5) + (pix & 7) + img * 3) & 15;
      const float* wt = w + ((size_t)(ky * 5 + kx) * 64) * 128 + co0;
#pragma unroll
      for (int g4 = 0; g4 < 16; ++g4) {
        float4 a = tb[pix * 16 + (g4 ^ s4)];
        a.x = valid ? a.x : 0.f; a.y = valid ? a.y : 0.f;
        a.z = valid ? a.z : 0.f; a.w = valid ? a.w : 0.f;
        const float av[4] = {a.x, a.y, a.z, a.w};
#pragma unroll
        for (int j = 0; j < 4; ++j) {
          const float* wp = wt + (g4 * 4 + j) * 128;
#pragma unroll
          for (int c = 0; c < 16; ++c) acc[c] = fmaf(av[j], wp[c], acc[c]);
        }
      }
    }
  }
  float* op = out + ((size_t)(b0 + img) * 16 + pos) * 128 + co0;
#pragma unroll
  for (int c = 0; c < 16; ++c) {
    const float v = fmaxf(acc[c] + bb[co0 + c], 0.f);
    op[c] = v * sc[co0 + c] + of[co0 + c];
  }
}

// ---------------------------------------------------------------------------
// fc_z
// ---------------------------------------------------------------------------
__global__ __launch_bounds__(256) void k_fcz(const float* __restrict__ h3,
    const float* __restrict__ wzm, const float* __restrict__ bzm,
    const float* __restrict__ wzl, const float* __restrict__ bzl,
    const float* __restrict__ eps, float* __restrict__ z) {
  __shared__ float a[4 * 256];
  const int ib = blockIdx.x * 4;
  const int tid = threadIdx.x;
  const int co = tid & 127;
  const int grp = __builtin_amdgcn_readfirstlane(tid >> 7);
  float am[2], al[2];
#pragma unroll
  for (int i = 0; i < 2; ++i) { am[i] = 0.f; al[i] = 0.f; }
  for (int kc = 0; kc < 2048; kc += 256) {
    __syncthreads();
    {
      const int r = tid >> 6, c4 = (tid & 63) << 2;
      *(float4*)&a[r * 256 + c4] =
          *(const float4*)&h3[(size_t)(ib + r) * 2048 + kc + c4];
    }
    __syncthreads();
#pragma unroll 4
    for (int k = 0; k < 256; k += 4) {
      float wm[4], wl[4];
#pragma unroll
      for (int q = 0; q < 4; ++q) {
        wm[q] = wzm[(size_t)(kc + k + q) * 128 + co];
        wl[q] = wzl[(size_t)(kc + k + q) * 128 + co];
      }
#pragma unroll
      for (int i = 0; i < 2; ++i) {
        const float4 av = *(const float4*)&a[(grp * 2 + i) * 256 + k];
        am[i] = fmaf(av.x, wm[0], am[i]); am[i] = fmaf(av.y, wm[1], am[i]);
        am[i] = fmaf(av.z, wm[2], am[i]); am[i] = fmaf(av.w, wm[3], am[i]);
        al[i] = fmaf(av.x, wl[0], al[i]); al[i] = fmaf(av.y, wl[1], al[i]);
        al[i] = fmaf(av.z, wl[2], al[i]); al[i] = fmaf(av.w, wl[3], al[i]);
      }
    }
  }
#pragma unroll
  for (int i = 0; i < 2; ++i) {
    const int row = ib + grp * 2 + i;
    const float zm = fmaxf(am[i] + bzm[co], 0.f);
    const float zl = fmaxf(al[i] + bzl[co], 0.f);
    z[(size_t)row * 128 + co] = zm + expf(0.5f * zl) * eps[(size_t)row * 128 + co];
  }
}

// ---------------------------------------------------------------------------
// fc_dec: z[C,128] @ dw[128,8192] -> d[C,8192]
// ---------------------------------------------------------------------------
__global__ __launch_bounds__(256) void k_fcdec(const float* __restrict__ z,
    const float* __restrict__ dw, const float* __restrict__ db,
    float* __restrict__ out) {
  __shared__ float4 zt4[2048];           // 32 KB
  const int bid = blockIdx.x;
  const int m0 = (bid >> 6) * 64;
  const int n0 = (bid & 63) * 128;
  const int tid = threadIdx.x;
#pragma unroll
  for (int q = 0; q < 8; ++q) {
    const int f4 = tid + q * 256;
    const int img = f4 >> 5, g4 = f4 & 31;
    const int s4 = (img * 5) & 31;
    zt4[img * 32 + (g4 ^ s4)] = ((const float4*)(z + (size_t)(m0) * 128))[f4];
  }
  __syncthreads();
  const int img = tid & 63;
  const int grp = __builtin_amdgcn_readfirstlane(tid >> 6);
  const int nb = n0 + grp * 32;
  const int s4 = (img * 5) & 31;
  float acc[32];
#pragma unroll
  for (int c = 0; c < 32; ++c) acc[c] = 0.f;
#pragma unroll
  for (int g4 = 0; g4 < 32; ++g4) {
    const float4 a = zt4[img * 32 + (g4 ^ s4)];
    const float av[4] = {a.x, a.y, a.z, a.w};
#pragma unroll
    for (int j = 0; j < 4; ++j) {
      const float* wp = dw + (size_t)(g4 * 4 + j) * 8192 + nb;
#pragma unroll
      for (int c = 0; c < 32; ++c) acc[c] = fmaf(av[j], wp[c], acc[c]);
    }
  }
  float* op = out + (size_t)(m0 + img) * 8192 + nb;
#pragma unroll
  for (int c = 0; c < 32; ++c) op[c] = fmaxf(acc[c] + db[nb + c], 0.f);
}

// ---------------------------------------------------------------------------
// convT1 1x1: d[C,8,8,128] -> t1[C,8,8,128]
// ---------------------------------------------------------------------------
__global__ __launch_bounds__(256) void k_tconv1(const float* __restrict__ in,
    const float* __restrict__ w, const float* __restrict__ bb,
    const float* __restrict__ sc, const float* __restrict__ of,
    float* __restrict__ out) {
  __shared__ float4 tile4[2048];         // 32 KB
  const int b = blockIdx.x;
  const int tid = threadIdx.x;
#pragma unroll
  for (int q = 0; q < 8; ++q) {
    const int f4 = tid + q * 256;
    const int pix = f4 >> 5, g4 = f4 & 31;
    const int s4 = (pix * 5) & 31;
    tile4[pix * 32 + (g4 ^ s4)] = ((const float4*)(in + (size_t)b * 8192))[f4];
  }
  __syncthreads();
  const int pos = tid & 63;
  const int chg = __builtin_amdgcn_readfirstlane(tid >> 6);
  const int co0 = chg * 32;
  const int s4 = (pos * 5) & 31;
  float acc[32];
#pragma unroll
  for (int c = 0; c < 32; ++c) acc[c] = 0.f;
#pragma unroll
  for (int g4 = 0; g4 < 32; ++g4) {
    const float4 a = tile4[pos * 32 + (g4 ^ s4)];
    const float av[4] = {a.x, a.y, a.z, a.w};
#pragma unroll
    for (int j = 0; j < 4; ++j) {
      const float* wp = w + (g4 * 4 + j) * 128 + co0;
#pragma unroll
      for (int c = 0; c < 32; ++c) acc[c] = fmaf(av[j], wp[c], acc[c]);
    }
  }
  float* op = out + ((size_t)b * 64 + pos) * 128 + co0;
#pragma unroll
  for (int c = 0; c < 32; ++c) {
    const float v = fmaxf(acc[c] + bb[co0 + c], 0.f);
    op[c] = v * sc[co0 + c] + of[co0 + c];
  }
}

// ---------------------------------------------------------------------------
// convT2: t1[C,8,8,128] -> t2g GROUPED [b][co/16][256 pix][16], unflipped s2.
// Epilogue: px-inner packing -> each thread stores one aligned 128 B line
// per py (fully coalesced, no partial-line RMW).
// ---------------------------------------------------------------------------
__global__ __launch_bounds__(256) void k_tconv2(const float* __restrict__ in,
    const float* __restrict__ w, const float* __restrict__ bb,
    const float* __restrict__ sc, const float* __restrict__ of,
    float* __restrict__ t2g) {
  __shared__ float4 tile4[2048];         // 32 KB
  const int b = blockIdx.x;
  const int tid = threadIdx.x;
#pragma unroll
  for (int q = 0; q < 8; ++q) {
    const int f4 = tid + q * 256;
    const int pix = f4 >> 5, g4 = f4 & 31;
    const int s4 = (pix * 5) & 31;
    tile4[pix * 32 + (g4 ^ s4)] = ((const float4*)(in + (size_t)b * 8192))[f4];
  }
  __syncthreads();
  const int pos = tid & 63;
  const int chg = __builtin_amdgcn_readfirstlane(tid >> 6);
  const int co0 = chg * 16;
  const int jy = pos >> 3, jx = pos & 7;
  float acc[4][16];
#pragma unroll
  for (int p = 0; p < 4; ++p)
#pragma unroll
    for (int c = 0; c < 16; ++c) acc[p][c] = 0.f;
  const int DY[9]  = {1,1,0,0,1,0,0,0,0};
  const int DX[9]  = {1,0,1,0,0,0,1,0,0};
  const int KYt[9] = {0,0,2,2,0,2,1,1,1};
  const int KXt[9] = {0,2,0,2,1,1,0,2,1};
  const int PHt[9] = {0,0,0,0,1,1,2,2,3};
#pragma unroll
  for (int t = 0; t < 9; ++t) {
    const int sy = jy - DY[t], sx = jx - DX[t];
    const bool valid = (sy >= 0) && (sx >= 0);
    const int pix = valid ? (sy * 8 + sx) : 0;
    const int s4 = (pix * 5) & 31;
    const int ph = PHt[t];
    const float* wt = w + ((size_t)(KYt[t] * 3 + KXt[t]) * 128) * 64 + co0;
#pragma unroll 2
    for (int g4 = 0; g4 < 32; ++g4) {
      float4 a = tile4[pix * 32 + (g4 ^ s4)];
      a.x = valid ? a.x : 0.f; a.y = valid ? a.y : 0.f;
      a.z = valid ? a.z : 0.f; a.w = valid ? a.w : 0.f;
      const float av[4] = {a.x, a.y, a.z, a.w};
#pragma unroll
      for (int j = 0; j < 4; ++j) {
        const float* wp = wt + (g4 * 4 + j) * 64;
#pragma unroll
        for (int c = 0; c < 16; ++c) acc[ph][c] = fmaf(av[j], wp[c], acc[ph][c]);
      }
    }
  }
#pragma unroll
  for (int py = 0; py < 2; ++py) {
    const int oy = 2 * jy + py;
    float vv[32];
#pragma unroll
    for (int px = 0; px < 2; ++px)
#pragma unroll
      for (int c = 0; c < 16; ++c) {
        const float v = fmaxf(acc[py * 2 + px][c] + bb[co0 + c], 0.f);
        vv[px * 16 + c] = v * sc[co0 + c] + of[co0 + c];
      }
    float* op = t2g + (((size_t)b * 4 + chg) * 256 + oy * 16 + 2 * jx) * 16;
#pragma unroll
    for (int q = 0; q < 8; ++q)
      *(float4*)&op[q * 4] = make_float4(vv[q*4+0], vv[q*4+1], vv[q*4+2], vv[q*4+3]);
  }
}

// ---------------------------------------------------------------------------
// convT3: t2g (grouped) -> t3g GROUPED [b][ci/8][1024 pix][8].
// 512 thr, 8-row slab +halo, dummy zero pixel; tap tables compile-time.
// ---------------------------------------------------------------------------
__global__ __launch_bounds__(512) void k_tconv3(const float* __restrict__ t2g,
    const float* __restrict__ w, const float* __restrict__ bb,
    const float* __restrict__ sc, const float* __restrict__ of,
    float* __restrict__ t3g) {
  __shared__ float4 tile4[145 * 16];     // 9 rows *16 cols *16 f4 + dummy pix
  const int b = blockIdx.x >> 1;
  const int r0 = (blockIdx.x & 1) * 8;
  const int tid = threadIdx.x;
  for (int f4 = tid; f4 < 2304; f4 += 512) {
    const int rr = f4 >> 8;              // 0..8
    const int col = (f4 >> 4) & 15, g4 = f4 & 15;
    const int gy = r0 - 1 + rr;
    float4 v = make_float4(0.f, 0.f, 0.f, 0.f);
    if (gy >= 0)
      v = ((const float4*)t2g)[(((size_t)b * 4 + (g4 >> 2)) * 256
                                + gy * 16 + col) * 4 + (g4 & 3)];
    const int s4 = (rr * 5 + col) & 15;
    tile4[(rr * 16 + col) * 16 + (g4 ^ s4)] = v;
  }
  if (tid < 16) tile4[144 * 16 + tid] = make_float4(0.f, 0.f, 0.f, 0.f);
  __syncthreads();
  const int pos = tid & 127;
  const int prow = pos >> 4, pcol = pos & 15;
  const int chg = __builtin_amdgcn_readfirstlane(tid >> 7);
  const int co0 = chg * 8;
  float acc[4][8];
#pragma unroll
  for (int p = 0; p < 4; ++p)
#pragma unroll
    for (int c = 0; c < 8; ++c) acc[p][c] = 0.f;
  const int DY[9]  = {1,1,0,0,1,0,0,0,0};
  const int DX[9]  = {1,0,1,0,0,0,1,0,0};
  const int KYt[9] = {0,0,2,2,0,2,1,1,1};
  const int KXt[9] = {0,2,0,2,1,1,0,2,1};
  const int PHt[9] = {0,0,0,0,1,1,2,2,3};
#pragma unroll
  for (int t = 0; t < 9; ++t) {
    const int syst = prow + 1 - DY[t];   // 0..8 staged (halo handled)
    const int sx = pcol - DX[t];
    const bool vx = (sx >= 0);
    const int pix = vx ? (syst * 16 + sx) : 144;
    const int s4 = vx ? ((syst * 5 + sx) & 15) : 0;
    const int ph = PHt[t];
    const float* wt = w + ((size_t)(KYt[t] * 3 + KXt[t]) * 64) * 32 + co0;
#pragma unroll 2
    for (int g4 = 0; g4 < 16; ++g4) {
      const float4 a = tile4[pix * 16 + (g4 ^ s4)];
      const float av[4] = {a.x, a.y, a.z, a.w};
#pragma unroll
      for (int j = 0; j < 4; ++j) {
        const float* wp = wt + (g4 * 4 + j) * 32;
#pragma unroll
        for (int c = 0; c < 8; ++c) acc[ph][c] = fmaf(av[j], wp[c], acc[ph][c]);
      }
    }
  }
  const int jy = r0 + prow;
#pragma unroll
  for (int py = 0; py < 2; ++py)
#pragma unroll
    for (int px = 0; px < 2; ++px) {
      const int oy = 2 * jy + py, ox = 2 * pcol + px;
      float* op = t3g + ((size_t)b * 4 + chg) * 8192 + (size_t)(oy * 32 + ox) * 8;
      float vv[8];
#pragma unroll
      for (int c = 0; c < 8; ++c) {
        const float v = fmaxf(acc[py * 2 + px][c] + bb[co0 + c], 0.f);
        vv[c] = v * sc[co0 + c] + of[co0 + c];
      }
      *(float4*)&op[0] = make_float4(vv[0], vv[1], vv[2], vv[3]);
      *(float4*)&op[4] = make_float4(vv[4], vv[5], vv[6], vv[7]);
    }
}

// ---------------------------------------------------------------------------
// convT4 + sigmoid + error (reads grouped t3g).
// ---------------------------------------------------------------------------
__global__ __launch_bounds__(256) void k_tconv4err(const float* __restrict__ t3g,
    const float* __restrict__ w, const float* __restrict__ bb,
    const float* __restrict__ x, float* __restrict__ err) {
  __shared__ float4 win4[34 * 65];
  const int b = blockIdx.x;
  const int tid = threadIdx.x;
  const int ty = tid >> 4, tx = tid & 15;
  float acc[2][2][3];
#pragma unroll
  for (int dy = 0; dy < 2; ++dy)
#pragma unroll
    for (int dx = 0; dx < 2; ++dx)
#pragma unroll
      for (int c = 0; c < 3; ++c) acc[dy][dx][c] = 0.f;
#pragma unroll 1
  for (int g = 0; g < 4; ++g) {
    __syncthreads();
    for (int f4 = tid; f4 < 2176; f4 += 256) {
      const int rr = f4 >> 6;
      const int rem = f4 & 63;
      const int col = rem >> 1, h = rem & 1;
      const int gy = rr - 1;
      float4 v = make_float4(0.f, 0.f, 0.f, 0.f);
      if ((unsigned)gy < 32u)
        v = ((const float4*)(t3g + ((size_t)b * 4 + g) * 8192))[(gy * 32 + col) * 2 + h];
      win4[rr * 65 + col * 2 + h] = v;
    }
    __syncthreads();
#pragma unroll 1
    for (int h = 0; h < 2; ++h) {
      float4 W[4][4];
#pragma unroll
      for (int wy = 0; wy < 4; ++wy)
#pragma unroll
        for (int wx = 0; wx < 4; ++wx) {
          const int col = 2 * tx - 1 + wx;
          const bool edge = (wx == 0) || (wx == 3);
          const bool v = edge ? ((unsigned)col < 32u) : true;
          const int cc = v ? col : 0;
          float4 t = win4[(2 * ty + wy) * 65 + cc * 2 + h];
          if (edge) {
            t.x = v ? t.x : 0.f; t.y = v ? t.y : 0.f;
            t.z = v ? t.z : 0.f; t.w = v ? t.w : 0.f;
          }
          W[wy][wx] = t;
        }
#pragma unroll
      for (int j = 0; j < 4; ++j) {
        const int ci = g * 8 + h * 4 + j;
#pragma unroll
        for (int ky = 0; ky < 3; ++ky)
#pragma unroll
          for (int kx = 0; kx < 3; ++kx) {
            const float* wp = w + ((ky * 3 + kx) * 32 + ci) * 3;
            const float w0 = wp[0], w1 = wp[1], w2 = wp[2];
#pragma unroll
            for (int dy = 0; dy < 2; ++dy)
#pragma unroll
              for (int dx = 0; dx < 2; ++dx) {
                const float4 t = W[dy + ky][dx + kx];
                const float av = (j == 0) ? t.x : (j == 1) ? t.y : (j == 2) ? t.z : t.w;
                acc[dy][dx][0] = fmaf(av, w0, acc[dy][dx][0]);
                acc[dy][dx][1] = fmaf(av, w1, acc[dy][dx][1]);
                acc[dy][dx][2] = fmaf(av, w2, acc[dy][dx][2]);
              }
          }
      }
    }
  }
#pragma unroll
  for (int dy = 0; dy < 2; ++dy)
#pragma unroll
    for (int dx = 0; dx < 2; ++dx) {
      const int oy = 2 * ty + dy, ox = 2 * tx + dx;
      const size_t pidx = (size_t)b * 1024 + oy * 32 + ox;
      float e = 0.f;
#pragma unroll
      for (int c = 0; c < 3; ++c) {
        const float pre = acc[dy][dx][c] + bb[c];
        float r;
        if (pre >= 0.f) {
          r = 1.f / (1.f + expf(-pre));
        } else {
          const float ex = expf(pre);
          r = ex / (1.f + ex);
        }
        const float dd = x[pidx * 3 + c] - r;
        e += dd * dd;
      }
      err[pidx] = e / 3.0f;
    }
}

// ---------------------------------------------------------------------------
// Otsu
// ---------------------------------------------------------------------------
__global__ __launch_bounds__(256) void k_otsu(const float* __restrict__ err,
                                              int* __restrict__ outmask) {
  __shared__ float e[2][1024];
  __shared__ float sig[2][81];
  __shared__ float opti[2];
  const int b0 = blockIdx.x * 2;
  const int tid = threadIdx.x;
  for (int f4 = tid; f4 < 512; f4 += 256) {
    const int img = f4 >> 8, idx = (f4 & 255) << 2;
    *(float4*)&e[img][idx] = *(const float4*)&err[(size_t)(b0 + img) * 1024 + idx];
  }
  __syncthreads();
  const int img = tid >> 7, j = tid & 127;
  if (j < 81) {
    const float t = (float)(0.1 + (double)j * 0.01);
    float n0 = 0.f, n1 = 0.f, s0 = 0.f, s1 = 0.f;
    for (int i = 0; i < 1024; ++i) {
      const float v = e[img][i];
      if (v < t) {
        if (v != 0.f) { n0 += 1.f; s0 += v; }
      } else {
        n1 += 1.f; s1 += v;
      }
    }
    const float nt = n0 + n1;
    float m0 = (s0 / 1024.f) * (nt / n0);
    if (m0 != m0) m0 = 0.f;
    float m1 = (s1 / 1024.f) * (nt / n1);
    if (m1 != m1) m1 = 0.f;
    const float p0 = n0 / nt, p1 = n1 / nt;
    const float dm = m0 - m1;
    sig[img][j] = p0 * p1 * (dm * dm);
  }
  __syncthreads();
  if (j == 0) {
    float smax = 0.f, op = 0.f;
    for (int jj = 0; jj < 81; ++jj) {
      const float sb = sig[img][jj];
      const float t = (float)(0.1 + (double)jj * 0.01);
      if (sb >= smax) { smax = sb; op = t; }
    }
    opti[img] = op;
  }
  __syncthreads();
#pragma unroll
  for (int q = 0; q < 8; ++q) {
    const int idx = tid + q * 256;
    const int im = idx >> 10, p = idx & 1023;
    outmask[(size_t)(b0 + im) * 1024 + p] = (e[im][p] < opti[im]) ? 1 : 0;
  }
}

// ============================================================================
extern "C" void kernel_launch(void* const* d_in, const int* in_sizes, int n_in,
                              void* d_out, int out_size, void* d_ws, size_t ws_size,
                              hipStream_t stream) {
  (void)in_sizes; (void)n_in; (void)out_size;
  const float* x    = (const float*)d_in[0];
  const float* eps  = (const float*)d_in[1];
  const float* ew1  = (const float*)d_in[2];
  const float* eb1  = (const float*)d_in[3];
  const float* es1  = (const float*)d_in[4];
  const float* eo1  = (const float*)d_in[5];
  const float* ew2  = (const float*)d_in[6];
  const float* eb2  = (const float*)d_in[7];
  const float* es2  = (const float*)d_in[8];
  const float* eo2  = (const float*)d_in[9];
  const float* ew3  = (const float*)d_in[10];
  const float* eb3  = (const float*)d_in[11];
  const float* es3  = (const float*)d_in[12];
  const float* eo3  = (const float*)d_in[13];
  const float* wzm  = (const float*)d_in[14];
  const float* bzm  = (const float*)d_in[15];
  const float* wzl  = (const float*)d_in[16];
  const float* bzl  = (const float*)d_in[17];
  const float* dw   = (const float*)d_in[18];
  const float* db   = (const float*)d_in[19];
  const float* tw1  = (const float*)d_in[20];
  const float* tb1  = (const float*)d_in[21];
  const float* ds1  = (const float*)d_in[22];
  const float* do1  = (const float*)d_in[23];
  const float* tw2  = (const float*)d_in[24];
  const float* tb2  = (const float*)d_in[25];
  const float* ds2  = (const float*)d_in[26];
  const float* do2  = (const float*)d_in[27];
  const float* tw3  = (const float*)d_in[28];
  const float* tb3  = (const float*)d_in[29];
  const float* ds3  = (const float*)d_in[30];
  const float* do3  = (const float*)d_in[31];
  const float* tw4  = (const float*)d_in[32];
  const float* tb4  = (const float*)d_in[33];
  int* mask = (int*)d_out;

  const size_t per_img_bytes = 233472;
  int C = 64;
  const int cand[6] = {4096, 2048, 1024, 512, 256, 128};
  for (int i = 0; i < 6; ++i) {
    if ((size_t)cand[i] * per_img_bytes <= ws_size) { C = cand[i]; break; }
  }

  float* p0 = (float*)d_ws;                       // C*32768 floats (h1|d|t3g)
  float* p1 = p0 + (size_t)C * 32768;             // C*8192  (h2|z|t1)
  float* p2 = p1 + (size_t)C * 8192;              // C*16384 (h3|t2g)
  float* p3 = p2 + (size_t)C * 16384;             // C*1024  (err)

  for (int c0 = 0; c0 < 4096; c0 += C) {
    const float* xc   = x   + (size_t)c0 * 3072;
    const float* epsc = eps + (size_t)c0 * 128;
    int*         mc   = mask + (size_t)c0 * 1024;
    float* h1 = p0;  float* dd = p0;  float* t3 = p0;
    float* h2 = p1;  float* zz = p1;  float* t1 = p1;
    float* h3 = p2;  float* t2 = p2;
    float* er = p3;

    k_conv1    <<<C,      256, 0, stream>>>(xc, ew1, eb1, es1, eo1, h1);
    k_conv2    <<<C,      256, 0, stream>>>(h1, ew2, eb2, es2, eo2, h2);
    k_conv3    <<<C / 4,  512, 0, stream>>>(h2, ew3, eb3, es3, eo3, h3);
    k_fcz      <<<C / 4,  256, 0, stream>>>(h3, wzm, bzm, wzl, bzl, epsc, zz);
    k_fcdec    <<<C,      256, 0, stream>>>(zz, dw, db, dd);
    k_tconv1   <<<C,      256, 0, stream>>>(dd, tw1, tb1, ds1, do1, t1);
    k_tconv2   <<<C,      256, 0, stream>>>(t1, tw2, tb2, ds2, do2, t2);
    k_tconv3   <<<C * 2,  512, 0, stream>>>(t2, tw3, tb3, ds3, do3, t3);
    k_tconv4err<<<C,      256, 0, stream>>>(t3, tw4, tb4, xc, er);
    k_otsu     <<<C / 2,  256, 0, stream>>>(er, mc);
  }
}